// Round 2
// baseline (150.632 us; speedup 1.0000x reference)
//
#include <hip/hip_runtime.h>
#include <math.h>

#define NB 16
#define NC 256
#define NHW 1024
#define NE 512
#define NDQ 4      // data qubits
#define NLQ 4      // layers
#define NQB 6      // qubits
#define QDIM 64
#define PIX 32     // pixels per block in main kernel
#define XPAD 260   // xs row stride in floats (1040 B, 16B-aligned)
#define MPAD 36    // ang/meas row stride in floats (144 B, 16B-aligned)

typedef float v2f __attribute__((ext_vector_type(2)));

// ---- CNOT-ring permutation (compile-time) ----
struct PermT { int v[QDIM]; };
constexpr PermT make_perm() {
    PermT P{};
    int f[QDIM] = {};
    for (int i = 0; i < QDIM; ++i) f[i] = i;
    for (int c = 0; c < NQB; ++c) {
        int t = (c + 1) % NQB;
        for (int i = 0; i < QDIM; ++i)
            if ((f[i] >> (NQB - 1 - c)) & 1) f[i] ^= 1 << (NQB - 1 - t);
    }
    for (int i = 0; i < QDIM; ++i) P.v[f[i]] = i;   // inverse map: new[i] = old[P.v[i]]
    return P;
}
constexpr PermT PERM = make_perm();

// ---- Kernel 1: GroupNorm stats (one block per (b, gn_group)) ----
__global__ __launch_bounds__(256) void k_stats(const float* __restrict__ x,
                                               float* __restrict__ mu,
                                               float* __restrict__ rs) {
    int bg = blockIdx.x;  // b*32 + g ; channels of group are contiguous
    const float4* xp = (const float4*)(x + (size_t)bg * 8 * NHW);
    float s = 0.f, ss = 0.f;
    for (int i = threadIdx.x; i < 8 * NHW / 4; i += 256) {
        float4 v = xp[i];
        s  += v.x + v.y + v.z + v.w;
        ss += v.x*v.x + v.y*v.y + v.z*v.z + v.w*v.w;
    }
    __shared__ float red0[4], red1[4];
    #pragma unroll
    for (int o = 32; o; o >>= 1) { s += __shfl_down(s, o); ss += __shfl_down(ss, o); }
    int lane = threadIdx.x & 63, w = threadIdx.x >> 6;
    if (lane == 0) { red0[w] = s; red1[w] = ss; }
    __syncthreads();
    if (threadIdx.x == 0) {
        s  = red0[0] + red0[1] + red0[2] + red0[3];
        ss = red1[0] + red1[1] + red1[2] + red1[3];
        float m = s * (1.f / 8192.f);
        float var = ss * (1.f / 8192.f) - m * m;
        mu[bg] = m;
        rs[bg] = rsqrtf(var + 1e-5f);
    }
}

// ---- Kernel 2: A[b][j] = theta[j] + silu(emb[b]) . w_style[j] + b_style[j] ----
__global__ __launch_bounds__(256) void k_style(const float* __restrict__ emb,
                                               const float* __restrict__ w_style,
                                               const float* __restrict__ b_style,
                                               const float* __restrict__ theta,
                                               float* __restrict__ A) {
    int b = blockIdx.x;
    __shared__ float es[NE];
    int t = threadIdx.x;
    for (int i = t; i < NE; i += 256) {
        float v = emb[b * NE + i];
        es[i] = v / (1.f + __expf(-v));
    }
    __syncthreads();
    int j0 = t >> 3, sub = t & 7;   // 8 lanes per output, 32 outputs per pass
    for (int pass = 0; pass < 6; ++pass) {
        int j = pass * 32 + j0;
        const float* wr = w_style + (size_t)j * NE + sub * 64;
        const float* er = es + sub * 64;
        float acc = 0.f;
        #pragma unroll
        for (int i = 0; i < 64; i += 4) {
            float4 w4 = *(const float4*)(wr + i);
            acc = fmaf(w4.x, er[i],   acc);
            acc = fmaf(w4.y, er[i+1], acc);
            acc = fmaf(w4.z, er[i+2], acc);
            acc = fmaf(w4.w, er[i+3], acc);
        }
        acc += __shfl_xor(acc, 1);
        acc += __shfl_xor(acc, 2);
        acc += __shfl_xor(acc, 4);
        if (sub == 0) A[b * 192 + j] = theta[j] + b_style[j] + acc;
    }
}

// extract logical element j (compile-time) from v2f-packed state
#define ELEM(arr, j) (((j) & 1) ? arr[(j) >> 1].y : arr[(j) >> 1].x)

// ---- Kernel 3: fused norm-apply + ang matvec + circuits + out matvec + residual ----
__global__ __launch_bounds__(256, 2) void k_main(const float* __restrict__ x,
                                                 const float* __restrict__ gamma,
                                                 const float* __restrict__ beta,
                                                 const float* __restrict__ w_in,
                                                 const float* __restrict__ b_in,
                                                 const float* __restrict__ A,
                                                 const float* __restrict__ w_out,
                                                 const float* __restrict__ b_out,
                                                 const float* __restrict__ mu,
                                                 const float* __restrict__ rs,
                                                 float* __restrict__ out) {
    __shared__ float xs[PIX * XPAD];   // normalized x, pixel-major [p][c], 32.5 KB
    __shared__ float as_[PIX * MPAD];  // ang  [p][o], 4.5 KB
    __shared__ float ms[PIX * MPAD];   // meas [p][o], 4.5 KB

    int blk = blockIdx.x;
    int b = blk >> 5;                 // 32 pixel-chunks per image
    int pbase = (blk & 31) * PIX;
    int t = threadIdx.x;

    // Phase 1: stage normalized x tile, TRANSPOSED to [p][c]
    {
        int c0 = t >> 3, f4 = (t & 7) * 4;
        #pragma unroll
        for (int k = 0; k < 8; ++k) {
            int c = c0 + 32 * k;
            int gidx = b * 32 + (c >> 3);
            float m = mu[gidx], r = rs[gidx];
            float sc = r * gamma[c];
            float sh = beta[c] - m * sc;
            float4 x4 = *(const float4*)(x + (size_t)(b * NC + c) * NHW + pbase + f4);
            xs[(f4 + 0) * XPAD + c] = fmaf(x4.x, sc, sh);
            xs[(f4 + 1) * XPAD + c] = fmaf(x4.y, sc, sh);
            xs[(f4 + 2) * XPAD + c] = fmaf(x4.z, sc, sh);
            xs[(f4 + 3) * XPAD + c] = fmaf(x4.w, sc, sh);
        }
    }
    __syncthreads();

    // Phase 2: ang[p][o] = w_in[o] . h[p][:] + b_in[o]; thread = (4 outputs, 1 pixel)
    {
        int og = t >> 5, p = t & 31;
        const float* wbase = w_in + og * 4 * NC;
        const float* hrow = xs + p * XPAD;
        float a0 = 0.f, a1 = 0.f, a2 = 0.f, a3 = 0.f;
        #pragma unroll 8
        for (int c = 0; c < NC; c += 4) {
            float4 h = *(const float4*)(hrow + c);
            float4 w0 = *(const float4*)(wbase + c);
            float4 w1 = *(const float4*)(wbase + NC + c);
            float4 w2 = *(const float4*)(wbase + 2 * NC + c);
            float4 w3 = *(const float4*)(wbase + 3 * NC + c);
            a0 = fmaf(w0.x, h.x, fmaf(w0.y, h.y, fmaf(w0.z, h.z, fmaf(w0.w, h.w, a0))));
            a1 = fmaf(w1.x, h.x, fmaf(w1.y, h.y, fmaf(w1.z, h.z, fmaf(w1.w, h.w, a1))));
            a2 = fmaf(w2.x, h.x, fmaf(w2.y, h.y, fmaf(w2.z, h.z, fmaf(w2.w, h.w, a2))));
            a3 = fmaf(w3.x, h.x, fmaf(w3.y, h.y, fmaf(w3.z, h.z, fmaf(w3.w, h.w, a3))));
        }
        float4 bi = *(const float4*)(b_in + og * 4);
        float4 r = {a0 + bi.x, a1 + bi.y, a2 + bi.z, a3 + bi.w};
        *(float4*)(as_ + p * MPAD + og * 4) = r;
    }
    __syncthreads();

    // Phase 3: quantum circuits — one thread per (pixel, group); state packed in v2f
    {
        int g = t >> 5, p = t & 31;
        float4 angv = *(const float4*)(as_ + p * MPAD + g * 4);
        float angp[NDQ] = {angv.x, angv.y, angv.z, angv.w};
        const float* Ab = A + b * 192 + g * 24;
        float Ar[24];
        #pragma unroll
        for (int j = 0; j < 24; ++j) Ar[j] = Ab[j];

        v2f st2[QDIM / 2];
        #pragma unroll
        for (int k = 0; k < QDIM / 2; ++k) st2[k] = (v2f){0.f, 0.f};
        st2[0].x = 1.f;

        #pragma unroll
        for (int l = 0; l < NLQ; ++l) {
            #pragma unroll
            for (int q = 0; q < NQB; ++q) {
                float a = Ar[l * NQB + q] + (q < NDQ ? angp[q] : 0.f);
                float sn, cs;
                __sincosf(0.5f * a, &sn, &cs);
                v2f cs2 = {cs, cs};
                if (q < 5) {
                    const int m = 32 >> q;      // >= 2: pairs align with v2f packing
                    v2f sn2 = {sn, sn};
                    #pragma unroll
                    for (int i = 0; i < QDIM; i += 2) {
                        if (i & m) continue;
                        int klo = i >> 1, khi = (i | m) >> 1;
                        v2f lo = st2[klo], hi = st2[khi];
                        v2f tm = sn2 * hi;
                        v2f um = cs2 * hi;
                        st2[klo] = __builtin_elementwise_fma(cs2, lo, -tm);
                        st2[khi] = __builtin_elementwise_fma(sn2, lo, um);
                    }
                } else {
                    v2f msn = {-sn, sn};        // rotate within each v2f
                    #pragma unroll
                    for (int k = 0; k < QDIM / 2; ++k) {
                        v2f a0 = st2[k];
                        v2f asw = __builtin_shufflevector(a0, a0, 1, 0);
                        st2[k] = __builtin_elementwise_fma(msn, asw, cs2 * a0);
                    }
                }
            }
            // CNOT-ring permutation: new[i] = old[PERM[i]]  (register renaming)
            v2f nst[QDIM / 2];
            #pragma unroll
            for (int k = 0; k < QDIM / 2; ++k) {
                v2f n;
                n.x = ELEM(st2, PERM.v[2 * k]);
                n.y = ELEM(st2, PERM.v[2 * k + 1]);
                nst[k] = n;
            }
            #pragma unroll
            for (int k = 0; k < QDIM / 2; ++k) st2[k] = nst[k];
        }

        // measurement: signs depend only on bits 5..2 -> sum groups of 4 first
        float s4[16];
        #pragma unroll
        for (int h = 0; h < 16; ++h) {
            v2f p0 = st2[2 * h] * st2[2 * h];
            v2f p1 = st2[2 * h + 1] * st2[2 * h + 1];
            s4[h] = (p0.x + p0.y) + (p1.x + p1.y);
        }
        float meas[NDQ] = {0.f, 0.f, 0.f, 0.f};
        #pragma unroll
        for (int h = 0; h < 16; ++h) {
            #pragma unroll
            for (int d = 0; d < NDQ; ++d) {
                if ((h >> (3 - d)) & 1) meas[d] -= s4[h];
                else                    meas[d] += s4[h];
            }
        }
        float4 mv = {meas[0], meas[1], meas[2], meas[3]};
        *(float4*)(ms + p * MPAD + g * 4) = mv;
    }
    __syncthreads();

    // Phase 4: out[c][p] = w_out[c] . meas[p][:] + b_out[c] + x[c][p]
    {
        int cg = t >> 5, p = t & 31;
        float mreg[32];
        #pragma unroll
        for (int j = 0; j < 8; ++j) {
            float4 m4 = *(const float4*)(ms + p * MPAD + j * 4);
            mreg[4 * j] = m4.x; mreg[4 * j + 1] = m4.y;
            mreg[4 * j + 2] = m4.z; mreg[4 * j + 3] = m4.w;
        }
        #pragma unroll 4
        for (int c0 = 0; c0 < 32; ++c0) {
            int c = cg * 32 + c0;
            const float* wr = w_out + c * 32;
            float acc = 0.f;
            #pragma unroll
            for (int o = 0; o < 32; o += 4) {
                float4 w4 = *(const float4*)(wr + o);
                acc = fmaf(w4.x, mreg[o],     acc);
                acc = fmaf(w4.y, mreg[o + 1], acc);
                acc = fmaf(w4.z, mreg[o + 2], acc);
                acc = fmaf(w4.w, mreg[o + 3], acc);
            }
            size_t gidx = (size_t)(b * NC + c) * NHW + pbase + p;
            out[gidx] = acc + b_out[c] + x[gidx];
        }
    }
}

extern "C" void kernel_launch(void* const* d_in, const int* in_sizes, int n_in,
                              void* d_out, int out_size, void* d_ws, size_t ws_size,
                              hipStream_t stream) {
    const float* x       = (const float*)d_in[0];
    const float* emb     = (const float*)d_in[1];
    const float* gamma   = (const float*)d_in[2];
    const float* beta    = (const float*)d_in[3];
    const float* w_in    = (const float*)d_in[4];
    const float* b_in    = (const float*)d_in[5];
    const float* theta   = (const float*)d_in[6];
    const float* w_style = (const float*)d_in[7];
    const float* b_style = (const float*)d_in[8];
    const float* w_out   = (const float*)d_in[9];
    const float* b_out   = (const float*)d_in[10];
    float* out = (float*)d_out;

    float* ws = (float*)d_ws;
    float* mu = ws;           // 512
    float* rs = ws + 512;     // 512
    float* A  = ws + 1024;    // 16*192 = 3072

    k_stats<<<NB * 32, 256, 0, stream>>>(x, mu, rs);
    k_style<<<NB, 256, 0, stream>>>(emb, w_style, b_style, theta, A);
    k_main<<<NB * 32, 256, 0, stream>>>(x, gamma, beta, w_in, b_in, A,
                                        w_out, b_out, mu, rs, out);
}

// Round 4
// 138.501 us; speedup vs baseline: 1.0876x; 1.0876x over previous
//
#include <hip/hip_runtime.h>
#include <math.h>

#define NB 16
#define NC 256
#define NHW 1024
#define NE 512
#define NDQ 4
#define NLQ 4
#define NQB 6
#define QDIM 64
#define PIX 16     // pixels per k_main block
#define XPAD 260   // xs row stride (floats); bank shift 4 -> 2-way max (free)
#define MSP 20     // ms row stride

typedef float v2f __attribute__((ext_vector_type(2)));

// ---- CNOT-ring permutation (compile-time) ----
struct PermT { int v[QDIM]; };
constexpr PermT make_perm() {
    PermT P{};
    int f[QDIM] = {};
    for (int i = 0; i < QDIM; ++i) f[i] = i;
    for (int c = 0; c < NQB; ++c) {
        int t = (c + 1) % NQB;
        for (int i = 0; i < QDIM; ++i)
            if ((f[i] >> (NQB - 1 - c)) & 1) f[i] ^= 1 << (NQB - 1 - t);
    }
    for (int i = 0; i < QDIM; ++i) P.v[f[i]] = i;   // new[i] = old[P.v[i]]
    return P;
}
constexpr PermT PERM = make_perm();

#define ELEM(arr, j) (((j) & 1) ? arr[(j) >> 1].y : arr[(j) >> 1].x)

// ---- Kernel 1: fused GroupNorm stats (blk<512) + style matvec (blk>=512) ----
__global__ __launch_bounds__(256) void k_pre(const float* __restrict__ x,
                                             const float* __restrict__ emb,
                                             const float* __restrict__ w_style,
                                             const float* __restrict__ b_style,
                                             const float* __restrict__ theta,
                                             float* __restrict__ mu,
                                             float* __restrict__ rs,
                                             float* __restrict__ A) {
    if (blockIdx.x < 512) {
        // --- GroupNorm stats: one block per (b, gn_group) ---
        int bg = blockIdx.x;
        const float4* xp = (const float4*)(x + (size_t)bg * 8 * NHW);
        float s = 0.f, ss = 0.f;
        for (int i = threadIdx.x; i < 8 * NHW / 4; i += 256) {
            float4 v = xp[i];
            s  += v.x + v.y + v.z + v.w;
            ss += v.x*v.x + v.y*v.y + v.z*v.z + v.w*v.w;
        }
        __shared__ float red0[4], red1[4];
        #pragma unroll
        for (int o = 32; o; o >>= 1) { s += __shfl_down(s, o); ss += __shfl_down(ss, o); }
        int lane = threadIdx.x & 63, w = threadIdx.x >> 6;
        if (lane == 0) { red0[w] = s; red1[w] = ss; }
        __syncthreads();
        if (threadIdx.x == 0) {
            s  = red0[0] + red0[1] + red0[2] + red0[3];
            ss = red1[0] + red1[1] + red1[2] + red1[3];
            float m = s * (1.f / 8192.f);
            float var = ss * (1.f / 8192.f) - m * m;
            mu[bg] = m;
            rs[bg] = rsqrtf(var + 1e-5f);
        }
    } else {
        // --- style: A[b][j] = theta[j] + silu(emb[b]).w_style[j] + b_style[j] ---
        int b = blockIdx.x - 512;
        __shared__ float es[NE];
        int t = threadIdx.x;
        for (int i = t; i < NE; i += 256) {
            float v = emb[b * NE + i];
            es[i] = v / (1.f + __expf(-v));
        }
        __syncthreads();
        int j0 = t >> 3, sub = t & 7;
        for (int pass = 0; pass < 6; ++pass) {
            int j = pass * 32 + j0;
            const float* wr = w_style + (size_t)j * NE + sub * 64;
            const float* er = es + sub * 64;
            float acc = 0.f;
            #pragma unroll
            for (int i = 0; i < 64; i += 4) {
                float4 w4 = *(const float4*)(wr + i);
                acc = fmaf(w4.x, er[i],   acc);
                acc = fmaf(w4.y, er[i+1], acc);
                acc = fmaf(w4.z, er[i+2], acc);
                acc = fmaf(w4.w, er[i+3], acc);
            }
            acc += __shfl_xor(acc, 1);
            acc += __shfl_xor(acc, 2);
            acc += __shfl_xor(acc, 4);
            if (sub == 0) A[b * 192 + j] = theta[j] + b_style[j] + acc;
        }
    }
}

// ---- Kernel 2: fused main. grid = 1024 blocks x 256 thr, PIX=16, 4 blk/CU ----
__global__ __launch_bounds__(256, 4) void k_main(
    const float* __restrict__ x,
    const float* __restrict__ gamma,
    const float* __restrict__ beta,
    const float* __restrict__ w_in,
    const float* __restrict__ b_in,
    const float* __restrict__ A,
    const float* __restrict__ w_out,
    const float* __restrict__ b_out,
    const float* __restrict__ mu,
    const float* __restrict__ rs,
    float* __restrict__ out) {

    __shared__ float xs[PIX * XPAD];   // [p][c] normalized h, later raw-x stash; 16.6 KB
    __shared__ float as_[PIX * 36];    // ang [p][o], 2.3 KB
    __shared__ float ms[32 * MSP];     // meas [o][p], 2.5 KB
    __shared__ float scs[NC], shs[NC]; // per-channel scale/shift, 2 KB

    int blk = blockIdx.x;
    int b = blk >> 6;
    int pbase = (blk & 63) * PIX;
    int t = threadIdx.x;
    int c0 = t >> 2, f4 = (t & 3) * 4;   // P0/P1 ownership: 4 channels x 4 pixels

    // ---- P0: load x tile to registers (the only x read) ----
    float4 xr[4];
    #pragma unroll
    for (int k = 0; k < 4; ++k) {
        int c = c0 + 64 * k;
        xr[k] = *(const float4*)(x + (size_t)(b * NC + c) * NHW + pbase + f4);
    }
    // per-channel scale/shift (one channel per thread)
    {
        int g = b * 32 + (t >> 3);
        float r = rs[g], m = mu[g];
        float sc = r * gamma[t];
        scs[t] = sc;
        shs[t] = fmaf(-m, sc, beta[t]);
    }
    __syncthreads();

    // ---- P1: normalize regs -> xs [p][c] ----
    #pragma unroll
    for (int k = 0; k < 4; ++k) {
        int c = c0 + 64 * k;
        float sc = scs[c], sh = shs[c];
        float4 v = xr[k];
        xs[(f4 + 0) * XPAD + c] = fmaf(v.x, sc, sh);
        xs[(f4 + 1) * XPAD + c] = fmaf(v.y, sc, sh);
        xs[(f4 + 2) * XPAD + c] = fmaf(v.z, sc, sh);
        xs[(f4 + 3) * XPAD + c] = fmaf(v.w, sc, sh);
    }
    __syncthreads();

    // ---- P2: ang[p][o] = w_in[o].h[p][:] + b_in[o]; thread = (2 outputs, 1 pixel) ----
    {
        int og2 = t >> 4, p = t & 15;
        int o0 = 2 * og2;
        const float* w0r = w_in + o0 * NC;
        const float* w1r = w_in + (o0 + 1) * NC;
        const float* hrow = xs + p * XPAD;
        float a0 = 0.f, a1 = 0.f;
        #pragma unroll 8
        for (int c = 0; c < NC; c += 4) {
            float4 h = *(const float4*)(hrow + c);
            float4 w0 = *(const float4*)(w0r + c);
            float4 w1 = *(const float4*)(w1r + c);
            a0 = fmaf(w0.x, h.x, fmaf(w0.y, h.y, fmaf(w0.z, h.z, fmaf(w0.w, h.w, a0))));
            a1 = fmaf(w1.x, h.x, fmaf(w1.y, h.y, fmaf(w1.z, h.z, fmaf(w1.w, h.w, a1))));
        }
        as_[p * 36 + o0]     = a0 + b_in[o0];
        as_[p * 36 + o0 + 1] = a1 + b_in[o0 + 1];
    }
    __syncthreads();

    // ---- stash raw x into xs (P2 consumed it); frees register pressure for P3 ----
    #pragma unroll
    for (int k = 0; k < 4; ++k) {
        int c = c0 + 64 * k;
        float4 v = xr[k];
        xs[(f4 + 0) * XPAD + c] = v.x;
        xs[(f4 + 1) * XPAD + c] = v.y;
        xs[(f4 + 2) * XPAD + c] = v.z;
        xs[(f4 + 3) * XPAD + c] = v.w;
    }

    // ---- P3: circuits, threads 0..127: (g = t>>4, p = t&15) ----
    if (t < 128) {
        int g = t >> 4, p = t & 15;
        float4 angv = *(const float4*)(as_ + p * 36 + g * 4);
        float angp[NDQ] = {angv.x, angv.y, angv.z, angv.w};
        float Ar[24];
        {
            const float4* Ab4 = (const float4*)(A + b * 192 + g * 24);
            #pragma unroll
            for (int j = 0; j < 6; ++j) {
                float4 a4 = Ab4[j];
                Ar[4*j] = a4.x; Ar[4*j+1] = a4.y; Ar[4*j+2] = a4.z; Ar[4*j+3] = a4.w;
            }
        }

        v2f st2[QDIM / 2];
        #pragma unroll
        for (int k = 0; k < QDIM / 2; ++k) st2[k] = (v2f){0.f, 0.f};
        st2[0].x = 1.f;

        #pragma unroll
        for (int l = 0; l < NLQ; ++l) {
            #pragma unroll
            for (int q = 0; q < NQB; ++q) {
                float a = Ar[l * NQB + q] + (q < NDQ ? angp[q] : 0.f);
                float sn, cs;
                __sincosf(0.5f * a, &sn, &cs);
                v2f cs2 = {cs, cs};
                if (q < 5) {
                    const int m = 32 >> q;
                    v2f sn2 = {sn, sn};
                    #pragma unroll
                    for (int i = 0; i < QDIM; i += 2) {
                        if (i & m) continue;
                        int klo = i >> 1, khi = (i | m) >> 1;
                        v2f lo = st2[klo], hi = st2[khi];
                        v2f tm = sn2 * hi;
                        v2f um = cs2 * hi;
                        st2[klo] = __builtin_elementwise_fma(cs2, lo, -tm);
                        st2[khi] = __builtin_elementwise_fma(sn2, lo, um);
                    }
                } else {
                    v2f msn = {-sn, sn};
                    #pragma unroll
                    for (int k = 0; k < QDIM / 2; ++k) {
                        v2f a0 = st2[k];
                        v2f asw = __builtin_shufflevector(a0, a0, 1, 0);
                        st2[k] = __builtin_elementwise_fma(msn, asw, cs2 * a0);
                    }
                }
            }
            v2f nst[QDIM / 2];
            #pragma unroll
            for (int k = 0; k < QDIM / 2; ++k) {
                v2f n;
                n.x = ELEM(st2, PERM.v[2 * k]);
                n.y = ELEM(st2, PERM.v[2 * k + 1]);
                nst[k] = n;
            }
            #pragma unroll
            for (int k = 0; k < QDIM / 2; ++k) st2[k] = nst[k];
        }

        float s4[16];
        #pragma unroll
        for (int h = 0; h < 16; ++h) {
            v2f p0 = st2[2 * h] * st2[2 * h];
            v2f p1 = st2[2 * h + 1] * st2[2 * h + 1];
            s4[h] = (p0.x + p0.y) + (p1.x + p1.y);
        }
        float meas[NDQ] = {0.f, 0.f, 0.f, 0.f};
        #pragma unroll
        for (int h = 0; h < 16; ++h) {
            #pragma unroll
            for (int d = 0; d < NDQ; ++d) {
                if ((h >> (3 - d)) & 1) meas[d] -= s4[h];
                else                    meas[d] += s4[h];
            }
        }
        #pragma unroll
        for (int d = 0; d < NDQ; ++d) ms[(g * 4 + d) * MSP + p] = meas[d];
    }
    __syncthreads();

    // ---- P4: out = w_out.meas + b_out + x; thread = (c2 = t>>3, 2 pixels f2) ----
    {
        int c2 = t >> 3, f2 = (t & 7) * 2;
        // cache meas for this thread's 2 pixels
        v2f mreg[32];
        #pragma unroll
        for (int o = 0; o < 32; ++o)
            mreg[o] = *(const v2f*)(ms + o * MSP + f2);
        #pragma unroll
        for (int k = 0; k < 8; ++k) {
            int c = c2 + 32 * k;
            const float* wr = w_out + c * 32;
            float ax = 0.f, ay = 0.f;
            #pragma unroll
            for (int o = 0; o < 32; o += 4) {
                float4 w4 = *(const float4*)(wr + o);
                v2f m0 = mreg[o], m1 = mreg[o+1], m2 = mreg[o+2], m3 = mreg[o+3];
                ax = fmaf(w4.x, m0.x, fmaf(w4.y, m1.x, fmaf(w4.z, m2.x, fmaf(w4.w, m3.x, ax))));
                ay = fmaf(w4.x, m0.y, fmaf(w4.y, m1.y, fmaf(w4.z, m2.y, fmaf(w4.w, m3.y, ay))));
            }
            float bo = b_out[c];
            float x0 = xs[(f2 + 0) * XPAD + c];
            float x1 = xs[(f2 + 1) * XPAD + c];
            float2 r = {ax + bo + x0, ay + bo + x1};
            *(float2*)(out + (size_t)(b * NC + c) * NHW + pbase + f2) = r;
        }
    }
}

extern "C" void kernel_launch(void* const* d_in, const int* in_sizes, int n_in,
                              void* d_out, int out_size, void* d_ws, size_t ws_size,
                              hipStream_t stream) {
    const float* x       = (const float*)d_in[0];
    const float* emb     = (const float*)d_in[1];
    const float* gamma   = (const float*)d_in[2];
    const float* beta    = (const float*)d_in[3];
    const float* w_in    = (const float*)d_in[4];
    const float* b_in    = (const float*)d_in[5];
    const float* theta   = (const float*)d_in[6];
    const float* w_style = (const float*)d_in[7];
    const float* b_style = (const float*)d_in[8];
    const float* w_out   = (const float*)d_in[9];
    const float* b_out   = (const float*)d_in[10];
    float* out = (float*)d_out;

    float* ws = (float*)d_ws;
    float* mu = ws;           // 512
    float* rs = ws + 512;     // 512
    float* A  = ws + 1024;    // 3072

    k_pre<<<512 + NB, 256, 0, stream>>>(x, emb, w_style, b_style, theta, mu, rs, A);
    k_main<<<NB * 64, 256, 0, stream>>>(x, gamma, beta, w_in, b_in, A,
                                        w_out, b_out, mu, rs, out);
}